// Round 1
// baseline (437.825 us; speedup 1.0000x reference)
//
#include <hip/hip_runtime.h>
#include <math.h>

#define W 4096
#define S 4096
#define NK_MAX 1024

// ---------------------------------------------------------------------------
// ws layout (floats):
//   [0,     8192)  : key table float2[4096]  (cos, sin) of 2*pi*k/4096
//   [8192, 12288)  : nm_re[4096]
//   [12288,16384)  : nm_im[4096]
//   [16384,17408)  : corr[1024]
//   [17408,18432)  : att[1024]
//   [18432,22528)  : ck_re[4096]
//   [22528,26624)  : ck_im[4096]
// total ~104 KB
// ---------------------------------------------------------------------------

// Stage 0: exact key table. keys[n,w] = exp(2*pi*i * ((w*(n+1)) mod W)/W),
// so only W distinct complex values exist. fp64 sincos once -> no range
// reduction error for large phases.
__global__ void table_kernel(float2* __restrict__ table) {
    int k = blockIdx.x * blockDim.x + threadIdx.x;
    if (k >= W) return;
    double theta = (double)k * (6.283185307179586 / (double)W);
    table[k] = make_float2((float)cos(theta), (float)sin(theta));
}

// Stage 1: noisy_mix[w] = sum_s holo[w,s]*conj(cue[w,s]).
// One block per row; float4 loads; wave+LDS reduction.
__global__ void nm_kernel(const float* __restrict__ hr, const float* __restrict__ hi,
                          const float* __restrict__ cr, const float* __restrict__ ci,
                          float* __restrict__ nmre, float* __restrict__ nmim) {
    int w = blockIdx.x;
    size_t base4 = (size_t)w * (S / 4);
    const float4* h4r = (const float4*)hr + base4;
    const float4* h4i = (const float4*)hi + base4;
    const float4* c4r = (const float4*)cr + base4;
    const float4* c4i = (const float4*)ci + base4;

    float sr = 0.f, si = 0.f;
    for (int i = threadIdx.x; i < S / 4; i += 256) {
        float4 a = h4r[i], b = h4i[i], c = c4r[i], d = c4i[i];
        // (hr + i*hi)(cr - i*ci): re = hr*cr + hi*ci ; im = hi*cr - hr*ci
        sr += a.x * c.x + b.x * d.x + a.y * c.y + b.y * d.y
            + a.z * c.z + b.z * d.z + a.w * c.w + b.w * d.w;
        si += b.x * c.x - a.x * d.x + b.y * c.y - a.y * d.y
            + b.z * c.z - a.z * d.z + b.w * c.w - a.w * d.w;
    }
    for (int off = 32; off; off >>= 1) {
        sr += __shfl_down(sr, off);
        si += __shfl_down(si, off);
    }
    __shared__ float s0[4], s1[4];
    int lane = threadIdx.x & 63, wid = threadIdx.x >> 6;
    if (lane == 0) { s0[wid] = sr; s1[wid] = si; }
    __syncthreads();
    if (threadIdx.x == 0) {
        nmre[w] = s0[0] + s0[1] + s0[2] + s0[3];
        nmim[w] = s1[0] + s1[1] + s1[2] + s1[3];
    }
}

// Stage 2: correlations[n] = |sum_w keys[n,w]*noisy_mix[w]| (no conjugation,
// matching torch.dot / keys @ noisy_mix). One block per key.
__global__ void corr_kernel(const float* __restrict__ nmre, const float* __restrict__ nmim,
                            const float2* __restrict__ table,
                            float* __restrict__ corr, const int* __restrict__ nkp) {
    int n = blockIdx.x;
    if (n >= *nkp) return;
    int f = n + 1;
    float sr = 0.f, si = 0.f;
    for (int w = threadIdx.x; w < W; w += 256) {
        int idx = (w * f) & (W - 1);
        float2 t = table[idx];
        float nr = nmre[w], ni = nmim[w];
        // (c + i*s)(nr + i*ni)
        sr += t.x * nr - t.y * ni;
        si += t.x * ni + t.y * nr;
    }
    for (int off = 32; off; off >>= 1) {
        sr += __shfl_down(sr, off);
        si += __shfl_down(si, off);
    }
    __shared__ float s0[4], s1[4];
    int lane = threadIdx.x & 63, wid = threadIdx.x >> 6;
    if (lane == 0) { s0[wid] = sr; s1[wid] = si; }
    __syncthreads();
    if (threadIdx.x == 0) {
        float r = s0[0] + s0[1] + s0[2] + s0[3];
        float m = s1[0] + s1[1] + s1[2] + s1[3];
        corr[n] = sqrtf(r * r + m * m);
    }
}

// Stage 3: stable softmax(corr * 50) over n_keys. Single block of 1024.
__global__ void softmax_kernel(const float* __restrict__ corr, float* __restrict__ att,
                               const int* __restrict__ nkp) {
    int n = threadIdx.x;
    int nk = *nkp;
    float v = (n < nk) ? corr[n] * 50.0f : -INFINITY;

    float m = v;
    for (int off = 32; off; off >>= 1) m = fmaxf(m, __shfl_down(m, off));
    __shared__ float sm[16];
    int lane = n & 63, wid = n >> 6;
    if (lane == 0) sm[wid] = m;
    __syncthreads();
    if (wid == 0) {
        float mm = (lane < 16) ? sm[lane] : -INFINITY;
        for (int off = 8; off; off >>= 1) mm = fmaxf(mm, __shfl_down(mm, off));
        if (lane == 0) sm[0] = mm;
    }
    __syncthreads();
    float M = sm[0];

    float e = (n < nk) ? expf(v - M) : 0.0f;
    float s = e;
    for (int off = 32; off; off >>= 1) s += __shfl_down(s, off);
    __shared__ float ss[16];
    if (lane == 0) ss[wid] = s;
    __syncthreads();
    if (wid == 0) {
        float t = (lane < 16) ? ss[lane] : 0.0f;
        for (int off = 8; off; off >>= 1) t += __shfl_down(t, off);
        if (lane == 0) ss[0] = t;
    }
    __syncthreads();
    float denom = ss[0];
    if (n < nk) att[n] = e / denom;
}

// Stage 4: clean_key[w] = sum_n att[n]*keys[n,w]. One thread per w; the key
// index walks idx += w (mod W) per n, starting at w (n=0 -> (n+1)=1).
__global__ void cleankey_kernel(const float* __restrict__ att, const float2* __restrict__ table,
                                float* __restrict__ ckre, float* __restrict__ ckim,
                                const int* __restrict__ nkp) {
    int w = blockIdx.x * blockDim.x + threadIdx.x;
    int nk = *nkp;
    __shared__ float satt[NK_MAX];
    for (int i = threadIdx.x; i < nk && i < NK_MAX; i += blockDim.x) satt[i] = att[i];
    __syncthreads();
    if (w >= W) return;
    float cr = 0.f, ci = 0.f;
    int idx = w & (W - 1);
    for (int n = 0; n < nk; n++) {
        float2 t = table[idx];
        float a = satt[n];
        cr += a * t.x;
        ci += a * t.y;
        idx = (idx + w) & (W - 1);
    }
    ckre[w] = cr;
    ckim[w] = ci;
}

// Stage 5: out[0,w,s] = hr*ckr - hi*cki ; out[1,w,s] = hr*cki + hi*ckr.
__global__ void out_kernel(const float* __restrict__ hr, const float* __restrict__ hi,
                           const float* __restrict__ ckre, const float* __restrict__ ckim,
                           float* __restrict__ out) {
    size_t i = (size_t)blockIdx.x * blockDim.x + threadIdx.x;  // float4 index
    const size_t total4 = (size_t)W * S / 4;
    if (i >= total4) return;
    int w = (int)(i >> 10);  // S/4 == 1024 float4s per row
    float cr = ckre[w], ci = ckim[w];
    float4 a = ((const float4*)hr)[i];
    float4 b = ((const float4*)hi)[i];
    float4 re, im;
    re.x = a.x * cr - b.x * ci;  im.x = a.x * ci + b.x * cr;
    re.y = a.y * cr - b.y * ci;  im.y = a.y * ci + b.y * cr;
    re.z = a.z * cr - b.z * ci;  im.z = a.z * ci + b.z * cr;
    re.w = a.w * cr - b.w * ci;  im.w = a.w * ci + b.w * cr;
    ((float4*)out)[i] = re;
    ((float4*)out)[i + total4] = im;  // imag plane starts at W*S floats
}

extern "C" void kernel_launch(void* const* d_in, const int* in_sizes, int n_in,
                              void* d_out, int out_size, void* d_ws, size_t ws_size,
                              hipStream_t stream) {
    const float* hr = (const float*)d_in[0];
    const float* hi = (const float*)d_in[1];
    const float* cr = (const float*)d_in[2];
    const float* ci = (const float*)d_in[3];
    const int* nk = (const int*)d_in[4];

    float* ws = (float*)d_ws;
    float2* table = (float2*)ws;         // 4096 float2
    float* nmre = ws + 8192;
    float* nmim = ws + 12288;
    float* corr = ws + 16384;
    float* att  = ws + 17408;
    float* ckre = ws + 18432;
    float* ckim = ws + 22528;
    float* out = (float*)d_out;

    table_kernel<<<16, 256, 0, stream>>>(table);
    nm_kernel<<<W, 256, 0, stream>>>(hr, hi, cr, ci, nmre, nmim);
    corr_kernel<<<NK_MAX, 256, 0, stream>>>(nmre, nmim, table, corr, nk);
    softmax_kernel<<<1, 1024, 0, stream>>>(corr, att, nk);
    cleankey_kernel<<<W / 256, 256, 0, stream>>>(att, table, ckre, ckim, nk);
    out_kernel<<<(W * S / 4) / 256, 256, 0, stream>>>(hr, hi, ckre, ckim, out);
}

// Round 3
// 372.985 us; speedup vs baseline: 1.1738x; 1.1738x over previous
//
#include <hip/hip_runtime.h>
#include <math.h>

#define W 4096
#define S 4096
#define NK_MAX 1024

typedef float v4f __attribute__((ext_vector_type(4)));  // clang vector — valid for nontemporal builtins

// ---------------------------------------------------------------------------
// ws layout (floats):
//   [0,     8192)  : key table float2[4096]  (cos,sin) of 2*pi*k/4096
//   [8192, 16384)  : nm    float2[4096]  (noisy_mix, interleaved re/im)
//   [16384,17408)  : corr  float[1024]
//   [17408,25600)  : ck    float2[4096]  (clean_key)
// ---------------------------------------------------------------------------

// Stage 0: exact key table (fp64 sincos of small phases -> no range-reduction
// error) + zero nm accumulators (ws is poisoned 0xAA before every launch).
__global__ void prep_kernel(float2* __restrict__ table, float2* __restrict__ nm) {
    int k = blockIdx.x * blockDim.x + threadIdx.x;
    if (k >= W) return;
    double theta = (double)k * (6.283185307179586 / (double)W);
    table[k] = make_float2((float)cos(theta), (float)sin(theta));
    nm[k] = make_float2(0.f, 0.f);
}

// Stage 1: noisy_mix[w] = sum_s holo[w,s]*conj(cue[w,s]).
// Flat streaming shape (same as out_kernel, which profiled faster than the
// per-row loop): 1 float4 per array per thread, block covers a quarter row,
// block-reduce then one atomicAdd pair.
__global__ void nm_kernel(const float* __restrict__ hr, const float* __restrict__ hi,
                          const float* __restrict__ cr, const float* __restrict__ ci,
                          float2* __restrict__ nm) {
    size_t i = (size_t)blockIdx.x * 256 + threadIdx.x;  // float4 index
    int w = (int)(i >> 10);                             // 1024 float4 per row; constant per block
    v4f a = ((const v4f*)hr)[i];
    v4f b = ((const v4f*)hi)[i];
    v4f c = ((const v4f*)cr)[i];
    v4f d = ((const v4f*)ci)[i];
    // (hr + i*hi)(cr - i*ci): re = hr*cr + hi*ci ; im = hi*cr - hr*ci
    v4f vr = a * c + b * d;
    v4f vi = b * c - a * d;
    float sr = vr.x + vr.y + vr.z + vr.w;
    float si = vi.x + vi.y + vi.z + vi.w;

    for (int off = 32; off; off >>= 1) {
        sr += __shfl_down(sr, off);
        si += __shfl_down(si, off);
    }
    __shared__ float s0[4], s1[4];
    int lane = threadIdx.x & 63, wid = threadIdx.x >> 6;
    if (lane == 0) { s0[wid] = sr; s1[wid] = si; }
    __syncthreads();
    if (threadIdx.x == 0) {
        atomicAdd(&nm[w].x, s0[0] + s0[1] + s0[2] + s0[3]);
        atomicAdd(&nm[w].y, s1[0] + s1[1] + s1[2] + s1[3]);
    }
}

// Stage 2: correlations[n] = |sum_w keys[n,w]*noisy_mix[w]| (no conjugation).
// One block per key; table/nm are L1/L2-hot (32 KB each).
__global__ void corr_kernel(const float2* __restrict__ nm, const float2* __restrict__ table,
                            float* __restrict__ corr, const int* __restrict__ nkp) {
    int n = blockIdx.x;
    if (n >= *nkp) return;
    int f = n + 1;
    float sr = 0.f, si = 0.f;
    for (int w = threadIdx.x; w < W; w += 256) {
        int idx = (w * f) & (W - 1);
        float2 t = table[idx];
        float2 v = nm[w];
        sr += t.x * v.x - t.y * v.y;
        si += t.x * v.y + t.y * v.x;
    }
    for (int off = 32; off; off >>= 1) {
        sr += __shfl_down(sr, off);
        si += __shfl_down(si, off);
    }
    __shared__ float s0[4], s1[4];
    int lane = threadIdx.x & 63, wid = threadIdx.x >> 6;
    if (lane == 0) { s0[wid] = sr; s1[wid] = si; }
    __syncthreads();
    if (threadIdx.x == 0) {
        float r = s0[0] + s0[1] + s0[2] + s0[3];
        float m = s1[0] + s1[1] + s1[2] + s1[3];
        corr[n] = sqrtf(r * r + m * m);
    }
}

// Stage 3+4 fused: each block recomputes softmax(corr*50) (deterministic,
// identical in every block), then computes clean_key for 64 rows with the
// key table staged in LDS (kills the global-latency-bound serial loop that
// dominated R1). 4 threads per row, 256 keys each, shuffle-combine.
__global__ void ck_kernel(const float* __restrict__ corr, const float2* __restrict__ table,
                          float2* __restrict__ ck, const int* __restrict__ nkp) {
    __shared__ float2 stab[W];       // 32 KB
    __shared__ float satt[NK_MAX];   // 4 KB
    __shared__ float red[8];
    int t = threadIdx.x;
    int nk = *nkp;
    int lane = t & 63, wid = t >> 6;

    for (int i = t; i < W; i += 256) stab[i] = table[i];

    // --- block softmax over corr[0..nk) ---
    float v[4];
    float vmax = -INFINITY;
    for (int j = 0; j < 4; j++) {
        int i = t + j * 256;
        v[j] = (i < nk) ? corr[i] * 50.0f : -INFINITY;
        vmax = fmaxf(vmax, v[j]);
    }
    for (int off = 32; off; off >>= 1) vmax = fmaxf(vmax, __shfl_down(vmax, off));
    if (lane == 0) red[wid] = vmax;
    __syncthreads();
    float M = fmaxf(fmaxf(red[0], red[1]), fmaxf(red[2], red[3]));
    __syncthreads();

    float esum = 0.f;
    for (int j = 0; j < 4; j++) {
        int i = t + j * 256;
        float e = (i < nk) ? expf(v[j] - M) : 0.f;
        if (i < NK_MAX) satt[i] = e;
        esum += e;
    }
    for (int off = 32; off; off >>= 1) esum += __shfl_down(esum, off);
    if (lane == 0) red[4 + wid] = esum;
    __syncthreads();
    float SUM = red[4] + red[5] + red[6] + red[7];
    // satt holds unnormalized exp; divide by SUM at the end (linear op).

    // --- clean_key: 64 rows per block, 4 threads per row ---
    int wl = t >> 2, sub = t & 3;
    int w = blockIdx.x * 64 + wl;
    int n0 = sub * 256;
    float crr = 0.f, cii = 0.f;
    int idx = (int)(((long long)w * (n0 + 1)) & (W - 1));
    int nend = min(n0 + 256, nk);
    for (int n = n0; n < nend; n++) {
        float2 tt = stab[idx];
        float a = satt[n];
        crr += a * tt.x;
        cii += a * tt.y;
        idx = (idx + w) & (W - 1);
    }
    // combine the 4 sub-partials (lanes t^1, t^2 are in the same wave)
    crr += __shfl_xor(crr, 1); cii += __shfl_xor(cii, 1);
    crr += __shfl_xor(crr, 2); cii += __shfl_xor(cii, 2);
    if (sub == 0 && w < W) ck[w] = make_float2(crr / SUM, cii / SUM);
}

// Stage 5: out[0,w,s] = hr*ckr - hi*cki ; out[1,w,s] = hr*cki + hi*ckr.
// NT stores: output is written once, never re-read on device — keep it out
// of LLC so the inputs stay resident for the next replay.
__global__ void out_kernel(const float* __restrict__ hr, const float* __restrict__ hi,
                           const float2* __restrict__ ck, float* __restrict__ out) {
    size_t i = (size_t)blockIdx.x * 256 + threadIdx.x;  // float4 index
    const size_t total4 = (size_t)W * S / 4;
    int w = (int)(i >> 10);
    float2 c = ck[w];
    v4f a = ((const v4f*)hr)[i];
    v4f b = ((const v4f*)hi)[i];
    v4f re = a * c.x - b * c.y;
    v4f im = a * c.y + b * c.x;
    __builtin_nontemporal_store(re, &((v4f*)out)[i]);
    __builtin_nontemporal_store(im, &((v4f*)out)[i + total4]);
}

extern "C" void kernel_launch(void* const* d_in, const int* in_sizes, int n_in,
                              void* d_out, int out_size, void* d_ws, size_t ws_size,
                              hipStream_t stream) {
    const float* hr = (const float*)d_in[0];
    const float* hi = (const float*)d_in[1];
    const float* cr = (const float*)d_in[2];
    const float* ci = (const float*)d_in[3];
    const int* nk = (const int*)d_in[4];

    float* ws = (float*)d_ws;
    float2* table = (float2*)ws;            // [0, 8192)
    float2* nm    = (float2*)(ws + 8192);   // [8192, 16384)
    float* corr   = ws + 16384;             // [16384, 17408)
    float2* ck    = (float2*)(ws + 17408);  // [17408, 25600)
    float* out = (float*)d_out;

    prep_kernel<<<W / 256, 256, 0, stream>>>(table, nm);
    nm_kernel<<<(size_t)W * S / 4 / 256, 256, 0, stream>>>(hr, hi, cr, ci, nm);
    corr_kernel<<<NK_MAX, 256, 0, stream>>>(nm, table, corr, nk);
    ck_kernel<<<W / 64, 256, 0, stream>>>(corr, table, ck, nk);
    out_kernel<<<(size_t)W * S / 4 / 256, 256, 0, stream>>>(hr, hi, ck, out);
}